// Round 1
// baseline (57.024 us; speedup 1.0000x reference)
//
#include <hip/hip_runtime.h>

#define TW 256        // output tile width  (== blockDim.x, one column/thread)
#define TH 50         // output tile height
#define IH 56         // TH + 6 staged input rows; 56 = 7*8 (clean ring unroll)
#define IW 262        // TW + 6 staged input cols
#define IWP 264       // padded LDS row, float4-multiple
#define NV4 (IWP/4)   // 66 float4 slots per row
#define W_IN 4096
#define H_IN 4096
#define W_OUT 4090
#define H_OUT 4090

__global__ __launch_bounds__(256, 2) void conv7x7(
    const float* __restrict__ x, const float* __restrict__ wgt,
    const float* __restrict__ bias, float* __restrict__ out)
{
    __shared__ float tile[IH][IWP];   // 56*264*4 = 59,136 B

    const int tx = threadIdx.x;
    const int x0 = blockIdx.x * TW;
    const int y0 = blockIdx.y * TH;

    // ---- weights + bias (wave-uniform) into registers ----
    float W[49];
    #pragma unroll
    for (int i = 0; i < 49; ++i) W[i] = wgt[i];
    const float bb = bias[0];

    // ---- stage input tile: coalesced float4 loads ----
    const int NSLOT = IH * NV4;       // 3696
    for (int slot = tx; slot < NSLOT; slot += 256) {
        const int r  = slot / NV4;    // const divisor -> magic mul
        const int c4 = slot - r * NV4;
        const int gy = y0 + r;
        const int gx = x0 + c4 * 4;
        float4 v;
        if (gy < H_IN && gx + 3 < W_IN) {
            v = *reinterpret_cast<const float4*>(x + gy * W_IN + gx);
        } else {
            v.x = (gy < H_IN && gx + 0 < W_IN) ? x[gy * W_IN + gx + 0] : 0.f;
            v.y = (gy < H_IN && gx + 1 < W_IN) ? x[gy * W_IN + gx + 1] : 0.f;
            v.z = (gy < H_IN && gx + 2 < W_IN) ? x[gy * W_IN + gx + 2] : 0.f;
            v.w = (gy < H_IN && gx + 3 < W_IN) ? x[gy * W_IN + gx + 3] : 0.f;
        }
        *reinterpret_cast<float4*>(&tile[r][c4 * 4]) = v;
    }
    __syncthreads();

    // ---- compute: stream rows, ring of 7 accumulators (all-static idx) ----
    const int gx_out = x0 + tx;
    const bool xok = (gx_out < W_OUT);

    float acc[7];
    #pragma unroll
    for (int s = 0; s < 7; ++s) acc[s] = 0.f;

    // prologue: input rows 0..6 (skip taps whose output row would be < 0)
    #pragma unroll
    for (int j = 0; j < 7; ++j) {
        float v[7];
        #pragma unroll
        for (int kx = 0; kx < 7; ++kx) v[kx] = tile[j][tx + kx];
        #pragma unroll
        for (int s = 0; s < 7; ++s) {
            const int ky = (j - s + 7) % 7;   // static
            if (ky <= j) {                    // static: oy = j-ky >= 0
                #pragma unroll
                for (int kx = 0; kx < 7; ++kx)
                    acc[s] += W[ky * 7 + kx] * v[kx];
            }
        }
    }
    // input row 6 completed output row 0 (slot 0)
    {
        const int gy = y0;
        if (xok && gy < H_OUT) out[gy * W_OUT + gx_out] = acc[0] + bb;
        acc[0] = 0.f;
    }

    // main: input rows 7..55, one output row completes per input row
    for (int rb = 1; rb < 8; ++rb) {
        #pragma unroll
        for (int j = 0; j < 7; ++j) {
            const int r = rb * 7 + j;
            float v[7];
            #pragma unroll
            for (int kx = 0; kx < 7; ++kx) v[kx] = tile[r][tx + kx];
            #pragma unroll
            for (int s = 0; s < 7; ++s) {
                const int ky = (j - s + 7) % 7;   // static per (j,s)
                #pragma unroll
                for (int kx = 0; kx < 7; ++kx)
                    acc[s] += W[ky * 7 + kx] * v[kx];
            }
            const int oy = r - 6;
            const int sc = (j + 1) % 7;           // static completing slot
            const int gy = y0 + oy;
            if (xok && gy < H_OUT) out[gy * W_OUT + gx_out] = acc[sc] + bb;
            acc[sc] = 0.f;
        }
    }
}

extern "C" void kernel_launch(void* const* d_in, const int* in_sizes, int n_in,
                              void* d_out, int out_size, void* d_ws, size_t ws_size,
                              hipStream_t stream) {
    const float* x   = (const float*)d_in[0];
    const float* w   = (const float*)d_in[1];
    const float* b   = (const float*)d_in[2];
    float* out = (float*)d_out;
    dim3 grid((W_OUT + TW - 1) / TW, (H_OUT + TH - 1) / TH);  // (16, 82)
    conv7x7<<<grid, 256, 0, stream>>>(x, w, b, out);
}

// Round 2
// 43.304 us; speedup vs baseline: 1.3168x; 1.3168x over previous
//
#include <hip/hip_runtime.h>

#define TW 512        // output tile width (2 cols per thread)
#define TH 13         // output tile height
#define IH 19         // TH + 6 staged input rows
#define IWP 520       // TW + 6 cols, padded to float4 multiple
#define NV4 (IWP/4)   // 130 float4 slots per row
#define W_IN 4096
#define H_IN 4096
#define W_OUT 4090
#define H_OUT 4090

__global__ __launch_bounds__(256, 4) void conv7x7(
    const float* __restrict__ x, const float* __restrict__ wgt,
    const float* __restrict__ bias, float* __restrict__ out)
{
    __shared__ float tile[IH][IWP];   // 19*520*4 = 39,520 B -> 4 blocks/CU

    const int tx = threadIdx.x;
    const int x0 = blockIdx.x * TW;
    const int y0 = blockIdx.y * TH;

    // ---- weights + bias (wave-uniform addresses -> scalarized) ----
    float W[49];
    #pragma unroll
    for (int i = 0; i < 49; ++i) W[i] = wgt[i];
    const float bb = bias[0];

    // ---- stage input tile: coalesced float4 loads ----
    const int NSLOT = IH * NV4;       // 2470
    for (int slot = tx; slot < NSLOT; slot += 256) {
        const int r  = slot / NV4;    // const divisor -> magic mul
        const int c4 = slot - r * NV4;
        const int gy = y0 + r;
        const int gx = x0 + c4 * 4;
        float4 v;
        if (gy < H_IN && gx + 3 < W_IN) {
            v = *reinterpret_cast<const float4*>(x + gy * W_IN + gx);
        } else {
            v.x = (gy < H_IN && gx + 0 < W_IN) ? x[gy * W_IN + gx + 0] : 0.f;
            v.y = (gy < H_IN && gx + 1 < W_IN) ? x[gy * W_IN + gx + 1] : 0.f;
            v.z = (gy < H_IN && gx + 2 < W_IN) ? x[gy * W_IN + gx + 2] : 0.f;
            v.w = (gy < H_IN && gx + 3 < W_IN) ? x[gy * W_IN + gx + 3] : 0.f;
        }
        *reinterpret_cast<float4*>(&tile[r][c4 * 4]) = v;
    }
    __syncthreads();

    // ---- compute: 2 columns/thread, ring of 7 accumulators, all-static ----
    const int cx = 2 * tx;            // local column of first output
    const int gx = x0 + cx;           // global column of first output

    float a0[7], a1[7];
    #pragma unroll
    for (int s = 0; s < 7; ++s) { a0[s] = 0.f; a1[s] = 0.f; }

    #pragma unroll
    for (int r = 0; r < IH; ++r) {
        // window: 8 consecutive floats starting at cx (8B-aligned -> ds_read_b64)
        float2 p0 = *reinterpret_cast<const float2*>(&tile[r][cx + 0]);
        float2 p1 = *reinterpret_cast<const float2*>(&tile[r][cx + 2]);
        float2 p2 = *reinterpret_cast<const float2*>(&tile[r][cx + 4]);
        float2 p3 = *reinterpret_cast<const float2*>(&tile[r][cx + 6]);
        const float f[8] = { p0.x, p0.y, p1.x, p1.y, p2.x, p2.y, p3.x, p3.y };

        #pragma unroll
        for (int ky = 0; ky < 7; ++ky) {
            const int oy = r - ky;            // static
            if (oy >= 0 && oy < TH) {         // static predicate
                const int s = oy % 7;         // static ring slot
                #pragma unroll
                for (int kx = 0; kx < 7; ++kx) {
                    a0[s] += W[ky * 7 + kx] * f[kx];
                    a1[s] += W[ky * 7 + kx] * f[kx + 1];
                }
            }
        }

        const int oy = r - 6;                 // output row completed by row r
        if (oy >= 0) {                        // static; oy < TH always (r <= 18)
            const int s = oy % 7;             // static
            const int gy = y0 + oy;
            if (gy < H_OUT) {
                if (gx + 1 < W_OUT) {
                    float2 o; o.x = a0[s] + bb; o.y = a1[s] + bb;
                    *reinterpret_cast<float2*>(&out[gy * W_OUT + gx]) = o;
                } else if (gx < W_OUT) {
                    out[gy * W_OUT + gx] = a0[s] + bb;
                }
            }
            a0[s] = 0.f; a1[s] = 0.f;
        }
    }
}

extern "C" void kernel_launch(void* const* d_in, const int* in_sizes, int n_in,
                              void* d_out, int out_size, void* d_ws, size_t ws_size,
                              hipStream_t stream) {
    const float* x   = (const float*)d_in[0];
    const float* w   = (const float*)d_in[1];
    const float* b   = (const float*)d_in[2];
    float* out = (float*)d_out;
    dim3 grid((W_OUT + TW - 1) / TW, (H_OUT + TH - 1) / TH);  // (8, 315)
    conv7x7<<<grid, 256, 0, stream>>>(x, w, b, out);
}